// Round 5
// baseline (328.666 us; speedup 1.0000x reference)
//
#include <hip/hip_runtime.h>
#include <cstdint>

#define S_LEN   2048
#define BATCH   4
#define NCH     4096                    // B*NH*HD channels
#define PLANE   ((size_t)S_LEN * NCH)   // per-gate plane: 8,388,608 elems
#define CHUNK   32
#define NCHUNK  64
#define SN      ((size_t)NCHUNK * NCH)  // 262144 summary slots
#define EPS     1e-8f

using bf16x8 = __attribute__((ext_vector_type(8))) short;
using f32x4  = __attribute__((ext_vector_type(4))) float;
typedef unsigned short u16;

__device__ __forceinline__ short f2bf(float f) {
  uint32_t u = __builtin_bit_cast(uint32_t, f);
  u += 0x7fffu + ((u >> 16) & 1u);
  return (short)(u >> 16);
}
__device__ __forceinline__ float bf2f(u16 u) {
  return __builtin_bit_cast(float, (uint32_t)u << 16);
}
// LDS-only barrier: orders ds ops without draining in-flight global loads.
__device__ __forceinline__ void lds_barrier() {
  asm volatile("s_waitcnt lgkmcnt(0)\n\ts_barrier" ::: "memory");
}

// ---------------------------------------------------------------------------
// Kernel 1: gate projection. R3 shape (1024 thr, per-tile stores, low VGPR ->
// 2 blocks/CU) + stride-272 LDS (0 conflicts) + depth-2 register prefetch +
// lds_barrier. Stores go to TRANSPOSED planes [ch][s]: each lane writes its
// 4 consecutive-s accs as one float4 (i,f) / ushort4 (z,o) -> per-instr
// 16 x 64B (fp32) or 16 x 32B (bf16) segments, L2-merged.
// ---------------------------------------------------------------------------
__global__ __launch_bounds__(1024) void gates_gemm5(
    const float* __restrict__ x, const float* __restrict__ W,
    const float* __restrict__ bias,
    u16* __restrict__ zT, float* __restrict__ iT, float* __restrict__ fT,
    u16* __restrict__ oT) {
  __shared__ u16 As[2][16 * 272];   // 2 x 8704 B

  const int gh  = blockIdx.x;          // g*4+h
  const int rg  = blockIdx.y;          // 0..31, 256 rows each
  const int g   = gh >> 2, hh = gh & 3;
  const int tid = threadIdx.x;
  const int wave = tid >> 6, lane = tid & 63;
  const int l16 = lane & 15, quad = lane >> 4;
  const int n0  = wave * 16;
  const int row0 = rg * 256;           // 8 row-blocks per batch b; same b all block

  // B fragments for this wave's 16-col strip
  bf16x8 Bf[8];
  {
    const float* wp = W + ((size_t)gh << 16) + (n0 + l16) * 256 + quad * 8;
#pragma unroll
    for (int kt = 0; kt < 8; ++kt) {
      float4 w0 = *(const float4*)(wp + kt * 32);
      float4 w1 = *(const float4*)(wp + kt * 32 + 4);
      bf16x8 b;
      b[0] = f2bf(w0.x); b[1] = f2bf(w0.y); b[2] = f2bf(w0.z); b[3] = f2bf(w0.w);
      b[4] = f2bf(w1.x); b[5] = f2bf(w1.y); b[6] = f2bf(w1.z); b[7] = f2bf(w1.w);
      Bf[kt] = b;
    }
  }
  const float bv = bias[gh * 256 + n0 + l16];

  // staging: thread tid loads float4 #tid of the 16x256 tile
  const int sr = tid >> 6, sc = tid & 63;
  const float* sbase = x + (size_t)(row0 + sr) * 4096 + g * 1024 + hh * 256 + sc * 4;

  auto swrite = [&](int buf, float4 v) {
    ushort4 u;
    u.x = (u16)f2bf(v.x); u.y = (u16)f2bf(v.y);
    u.z = (u16)f2bf(v.z); u.w = (u16)f2bf(v.w);
    *(ushort4*)&As[buf][sr * 272 + sc * 4] = u;
  };

  // transposed-store geometry (constant per lane)
  const int bb = row0 >> 11;                       // batch index
  const size_t ch = (size_t)bb * 1024 + hh * 256 + n0 + l16;
  const int sbase0 = (row0 & (S_LEN - 1)) + quad * 4;

  float4 pf[2];
  pf[0] = *(const float4*)(sbase);
  pf[1] = *(const float4*)(sbase + (size_t)16 * 4096);
  swrite(0, pf[0]);
  lds_barrier();

#pragma unroll
  for (int t = 0; t < 16; ++t) {
    if (t + 2 < 16) pf[t & 1] = *(const float4*)(sbase + (size_t)(t + 2) * 16 * 4096);

    f32x4 acc = (f32x4){0.f, 0.f, 0.f, 0.f};
#pragma unroll
    for (int kt = 0; kt < 8; ++kt) {
      bf16x8 a = *(const bf16x8*)&As[t & 1][l16 * 272 + kt * 32 + quad * 8];
      acc = __builtin_amdgcn_mfma_f32_16x16x32_bf16(a, Bf[kt], acc, 0, 0, 0);
    }

    // per-tile transposed store: 4 consecutive s per lane
    {
      const size_t off = ch * S_LEN + (size_t)(sbase0 + t * 16);
      float v0 = acc[0] + bv, v1 = acc[1] + bv, v2 = acc[2] + bv, v3 = acc[3] + bv;
      if (g == 1) {
        *(float4*)&iT[off] = make_float4(v0, v1, v2, v3);
      } else if (g == 2) {
        *(float4*)&fT[off] = make_float4(v0, v1, v2, v3);
      } else if (g == 0) {
        ushort4 u;
        u.x = (u16)f2bf(1.f - 2.f * __builtin_amdgcn_rcpf(1.f + __expf(2.f * v0)));
        u.y = (u16)f2bf(1.f - 2.f * __builtin_amdgcn_rcpf(1.f + __expf(2.f * v1)));
        u.z = (u16)f2bf(1.f - 2.f * __builtin_amdgcn_rcpf(1.f + __expf(2.f * v2)));
        u.w = (u16)f2bf(1.f - 2.f * __builtin_amdgcn_rcpf(1.f + __expf(2.f * v3)));
        *(ushort4*)&zT[off] = u;
      } else {
        ushort4 u;
        u.x = (u16)f2bf(__builtin_amdgcn_rcpf(1.f + __expf(-v0)));
        u.y = (u16)f2bf(__builtin_amdgcn_rcpf(1.f + __expf(-v1)));
        u.z = (u16)f2bf(__builtin_amdgcn_rcpf(1.f + __expf(-v2)));
        u.w = (u16)f2bf(__builtin_amdgcn_rcpf(1.f + __expf(-v3)));
        *(ushort4*)&oT[off] = u;
      }
    }

    if (t + 1 < 16) {
      swrite((t + 1) & 1, pf[(t + 1) & 1]);
      lds_barrier();
    }
  }
}

// ---------------------------------------------------------------------------
// Kernel 2: fused pass1+pass2. Wave = channel, lane = chunk. Each lane
// builds its 32-step locally-stabilized summary from time-contiguous
// transposed planes (float4 loads, private 128-B lines), then an in-wave
// Kogge-Stone scan composes the 64 summaries; entering (c,n,m) written.
// ---------------------------------------------------------------------------
__global__ __launch_bounds__(256, 4) void scan_pass12(
    const u16* __restrict__ zT, const float* __restrict__ iT,
    const float* __restrict__ fT, float* __restrict__ ent) {
  const int gt   = blockIdx.x * 256 + threadIdx.x;
  const int ch   = gt >> 6;            // 0..4095
  const int lane = threadIdx.x & 63;   // chunk
  const size_t base = (size_t)ch * S_LEN + (size_t)lane * CHUNK;

  float4  iv[8], fv[8];
  ushort4 zv[8];
#pragma unroll
  for (int j = 0; j < 8; ++j) iv[j] = *(const float4*)&iT[base + j * 4];
#pragma unroll
  for (int j = 0; j < 8; ++j) fv[j] = *(const float4*)&fT[base + j * 4];
#pragma unroll
  for (int j = 0; j < 8; ++j) zv[j] = *(const ushort4*)&zT[base + j * 4];

  float A = 0.f, B = -1e30f, D = 0.f, N = 0.f;
#pragma unroll
  for (int s = 0; s < 32; ++s) {
    float i = ((const float*)&iv[s >> 2])[s & 3];
    float f = ((const float*)&fv[s >> 2])[s & 3];
    float z = bf2f(((const u16*)&zv[s >> 2])[s & 3]);
    float Bn = fmaxf(B + f, i);
    float e1 = __expf(B + f - Bn);
    float e2 = __expf(i - Bn);
    D = e1 * D + e2 * z;
    N = e1 * N + e2;
    A += f;
    B = Bn;
  }

  // Kogge-Stone inclusive scan: compose (earlier)∘(self)
#pragma unroll
  for (int d = 1; d < 64; d <<= 1) {
    float A1 = __shfl_up(A, d, 64);
    float B1 = __shfl_up(B, d, 64);
    float D1 = __shfl_up(D, d, 64);
    float N1 = __shfl_up(N, d, 64);
    if (lane >= d) {
      float Bn = fmaxf(B1 + A, B);
      float s1 = __expf(B1 + A - Bn);
      float s2 = __expf(B - Bn);
      D = s1 * D1 + s2 * D;
      N = s1 * N1 + s2 * N;
      B = Bn;
      A = A1 + A;
    }
  }

  // exclusive prefix -> entering state from (c,n,m)=(0,0,0)
  float Ax = __shfl_up(A, 1, 64), Bx = __shfl_up(B, 1, 64);
  float Dx = __shfl_up(D, 1, 64), Nx = __shfl_up(N, 1, 64);
  if (lane == 0) { Ax = 0.f; Bx = -1e30f; Dx = 0.f; Nx = 0.f; }

  float mE = fmaxf(Ax, Bx);
  float sc = __expf(Bx - mE);
  const size_t idx = (size_t)lane * NCH + ch;
  ent[idx]          = sc * Dx;
  ent[SN + idx]     = sc * Nx;
  ent[2 * SN + idx] = mE;
}

// ---------------------------------------------------------------------------
// Kernel 3: pass 3 — load entering state, load the chunk's 32 steps as
// contiguous float4/ushort4 (private lines), replay the original recurrence,
// write h coalesced in [s][ch]. Last chunk writes finals.
// ---------------------------------------------------------------------------
__global__ __launch_bounds__(256, 4) void scan_pass3(
    const u16* __restrict__ zT, const float* __restrict__ iT,
    const float* __restrict__ fT, const u16* __restrict__ oT,
    const float* __restrict__ ent, float* __restrict__ out) {
  const int t  = blockIdx.x * 256 + threadIdx.x;
  const int ch = t & (NCH - 1);
  const int ck = t >> 12;

  const size_t idx0 = (size_t)ck * NCH + ch;
  float c = ent[idx0];
  float n = ent[SN + idx0];
  float m = ent[2 * SN + idx0];

  const size_t base = (size_t)ch * S_LEN + (size_t)ck * CHUNK;
  float4  iv[8], fv[8];
  ushort4 zv[8], ov[8];
#pragma unroll
  for (int j = 0; j < 8; ++j) iv[j] = *(const float4*)&iT[base + j * 4];
#pragma unroll
  for (int j = 0; j < 8; ++j) fv[j] = *(const float4*)&fT[base + j * 4];
#pragma unroll
  for (int j = 0; j < 8; ++j) zv[j] = *(const ushort4*)&zT[base + j * 4];
#pragma unroll
  for (int j = 0; j < 8; ++j) ov[j] = *(const ushort4*)&oT[base + j * 4];

  const int b = ch >> 10, d = ch & 1023;
  float* hout = out + (size_t)b * (S_LEN * 1024) + (size_t)(ck * CHUNK) * 1024 + d;

  float hv = 0.f;
#pragma unroll
  for (int s = 0; s < 32; ++s) {
    float i = ((const float*)&iv[s >> 2])[s & 3];
    float f = ((const float*)&fv[s >> 2])[s & 3];
    float z = bf2f(((const u16*)&zv[s >> 2])[s & 3]);
    float o = bf2f(((const u16*)&ov[s >> 2])[s & 3]);
    float mn = fmaxf(f + m, i);
    float fh = __expf(f + m - mn);
    float ih = __expf(i - mn);
    c = fh * c + ih * z;
    n = fh * n + ih;
    m = mn;
    hv = o * c * __builtin_amdgcn_rcpf(n + EPS);
    hout[(size_t)s * 1024] = hv;
  }

  if (ck == NCHUNK - 1) {
    float* fin = out + (size_t)BATCH * S_LEN * 1024;   // 8,388,608
    fin[ch]            = hv;
    fin[NCH + ch]      = c;
    fin[2 * NCH + ch]  = n;
    fin[3 * NCH + ch]  = m;
  }
}

extern "C" void kernel_launch(void* const* d_in, const int* in_sizes, int n_in,
                              void* d_out, int out_size, void* d_ws, size_t ws_size,
                              hipStream_t stream) {
  const float* x    = (const float*)d_in[0];   // [4,2048,4096] fp32
  const float* W    = (const float*)d_in[1];   // [4,4,256,256] fp32
  const float* bias = (const float*)d_in[2];   // [4,4,256] fp32
  float* out = (float*)d_out;

  // ws layout (all planes TRANSPOSED [ch][s]): z bf16 | i fp32 | f fp32 |
  // o bf16 | ent 3*SN fp32.  Total ~103.8 MB.
  u16*   zT  = (u16*)d_ws;                        // 16.78 MB
  float* iT  = (float*)(zT + PLANE);              // 33.55 MB
  float* fT  = iT + PLANE;                        // 33.55 MB
  u16*   oT  = (u16*)(fT + PLANE);                // 16.78 MB
  float* ent = (float*)(oT + PLANE);              // 3.15 MB

  gates_gemm5<<<dim3(16, 32), dim3(1024), 0, stream>>>(x, W, bias, zT, iT, fT, oT);
  scan_pass12<<<dim3(1024), dim3(256), 0, stream>>>(zT, iT, fT, ent);
  scan_pass3<<<dim3(1024), dim3(256), 0, stream>>>(zT, iT, fT, oT, ent, out);
}